// Round 1
// baseline (480.029 us; speedup 1.0000x reference)
//
#include <hip/hip_runtime.h>
#include <hip/hip_bf16.h>

#define BB 64
#define SS 8192
#define DD 128

typedef __attribute__((ext_vector_type(8))) short bf16x8;
typedef __attribute__((ext_vector_type(4))) short s16x4;
typedef __attribute__((ext_vector_type(4))) float f32x4;

__device__ __forceinline__ short f2bf(float f) {
    unsigned u = __float_as_uint(f);
    unsigned r = (u + 0x7FFFu + ((u >> 16) & 1u)) >> 16;
    return (short)r;
}

__device__ __forceinline__ float tanh_fast(float x) {
    // tanh(x) = 1 - 2/(e^{2x}+1); saturates to +/-1 without NaN
    float e = __expf(2.f * x);
    return 1.f - 2.f / (e + 1.f);
}

// ---------------- K1: q = tanh(input @ W_dec^T + b_dec); also zero wc accum
__global__ void qproj_kernel(const float* __restrict__ input,
                             const float* __restrict__ W_dec,
                             const float* __restrict__ b_dec,
                             float* __restrict__ q,
                             float* __restrict__ wc) {
    __shared__ float xin[DD];
    const int b = blockIdx.x, d = threadIdx.x;  // 128 threads
    xin[d] = input[b * DD + d];
    wc[b * DD + d] = 0.f;
    __syncthreads();
    const float4* wrow = (const float4*)(W_dec + (size_t)d * DD);
    float acc = 0.f;
#pragma unroll
    for (int k4 = 0; k4 < DD / 4; k4++) {
        float4 w = wrow[k4];
        float4 x = ((const float4*)xin)[k4];
        acc += w.x * x.x + w.y * x.y + w.z * x.z + w.w * x.w;
    }
    q[b * DD + d] = tanh_fast(acc + b_dec[d]);
}

// ---------------- K2: scores[b,s] = sum_d tanh((ctx@W_enc^T)[b,s,d] + b_enc[d]) * q[b,d]
#define MT 64     // s-rows per tile
#define LDW 136   // padded LDS row stride in bf16 elems (272 B) -> 2-way max conflicts

__global__ __launch_bounds__(256, 2) void score_kernel(
    const float* __restrict__ ctx,
    const float* __restrict__ W_enc,
    const float* __restrict__ b_enc,
    const float* __restrict__ q,
    float* __restrict__ scores_out) {
    __shared__ short Wl[DD * LDW];   // Wl[n][k] = bf16(W_enc[n*128+k]); B-operand = W_enc^T
    __shared__ short Cl[MT * LDW];   // ctx tile rows

    const int t = threadIdx.x;
    // stage W_enc (shared by every tile this block processes)
    for (int i = t; i < DD * 32; i += 256) {  // i indexes float4; 32 per row
        float4 f = ((const float4*)W_enc)[i];
        int row = i >> 5, c4 = i & 31;
        s16x4 pk = {f2bf(f.x), f2bf(f.y), f2bf(f.z), f2bf(f.w)};
        *(s16x4*)&Wl[row * LDW + c4 * 4] = pk;
    }

    const int wave = t >> 6, lane = t & 63;
    const int col = lane & 15, quad = lane >> 4;
    const int ntiles = BB * (SS / MT);  // 8192

    for (int tile = blockIdx.x; tile < ntiles; tile += gridDim.x) {
        const int b = tile >> 7;          // / (SS/MT) = 128
        const int st = tile & 127;

        __syncthreads();  // protect Cl (and first-iter Wl) before rewrite
        const float4* src = (const float4*)(ctx + ((size_t)b * SS + (size_t)st * MT) * DD);
        for (int i = t; i < MT * 32; i += 256) {
            float4 f = src[i];
            int row = i >> 5, c4 = i & 31;
            s16x4 pk = {f2bf(f.x), f2bf(f.y), f2bf(f.z), f2bf(f.w)};
            *(s16x4*)&Cl[row * LDW + c4 * 4] = pk;
        }
        __syncthreads();

        float qv[8], bv[8];
#pragma unroll
        for (int nt = 0; nt < 8; nt++) {
            qv[nt] = q[b * DD + nt * 16 + col];
            bv[nt] = b_enc[nt * 16 + col];
        }

        // A fragments: lane holds A[m=col][k = kk*32 + quad*8 + j]
        bf16x8 a[4];
#pragma unroll
        for (int kk = 0; kk < 4; kk++)
            a[kk] = *(const bf16x8*)&Cl[(wave * 16 + col) * LDW + kk * 32 + quad * 8];

        f32x4 acc[8];
#pragma unroll
        for (int nt = 0; nt < 8; nt++) {
            f32x4 c = {0.f, 0.f, 0.f, 0.f};
#pragma unroll
            for (int kk = 0; kk < 4; kk++) {
                // B fragment: lane holds B[k][n=col] = W_enc[n][k]
                bf16x8 bf = *(const bf16x8*)&Wl[(nt * 16 + col) * LDW + kk * 32 + quad * 8];
                c = __builtin_amdgcn_mfma_f32_16x16x32_bf16(a[kk], bf, c, 0, 0, 0);
            }
            acc[nt] = c;
        }

        // epilogue: tanh, dot with q, reduce over the 16 cols of each quad
#pragma unroll
        for (int r = 0; r < 4; r++) {
            float v = 0.f;
#pragma unroll
            for (int nt = 0; nt < 8; nt++) {
                float z = acc[nt][r] + bv[nt];
                v += tanh_fast(z) * qv[nt];
            }
            v += __shfl_xor(v, 1);
            v += __shfl_xor(v, 2);
            v += __shfl_xor(v, 4);
            v += __shfl_xor(v, 8);
            if (col == 0) {
                int srow = st * MT + wave * 16 + quad * 4 + r;
                scores_out[(size_t)b * SS + srow] = v;
            }
        }
    }
}

// ---------------- K3: in-place softmax over S per batch row (1 block/batch, 1024 thr)
__global__ __launch_bounds__(1024) void softmax_kernel(float* __restrict__ attn) {
    __shared__ float redm[16];
    __shared__ float reds[16];
    const int b = blockIdx.x, t = threadIdx.x;
    float4* row4 = (float4*)(attn + (size_t)b * SS);
    float4 v0 = row4[t];
    float4 v1 = row4[t + 1024];
    float m = fmaxf(fmaxf(fmaxf(v0.x, v0.y), fmaxf(v0.z, v0.w)),
                    fmaxf(fmaxf(v1.x, v1.y), fmaxf(v1.z, v1.w)));
#pragma unroll
    for (int off = 32; off; off >>= 1) m = fmaxf(m, __shfl_xor(m, off));
    if ((t & 63) == 0) redm[t >> 6] = m;
    __syncthreads();
    float M = redm[0];
#pragma unroll
    for (int i = 1; i < 16; i++) M = fmaxf(M, redm[i]);

    float4 e0, e1;
    e0.x = __expf(v0.x - M); e0.y = __expf(v0.y - M);
    e0.z = __expf(v0.z - M); e0.w = __expf(v0.w - M);
    e1.x = __expf(v1.x - M); e1.y = __expf(v1.y - M);
    e1.z = __expf(v1.z - M); e1.w = __expf(v1.w - M);
    float s = e0.x + e0.y + e0.z + e0.w + e1.x + e1.y + e1.z + e1.w;
#pragma unroll
    for (int off = 32; off; off >>= 1) s += __shfl_xor(s, off);
    if ((t & 63) == 0) reds[t >> 6] = s;
    __syncthreads();
    float T = 0.f;
#pragma unroll
    for (int i = 0; i < 16; i++) T += reds[i];
    float inv = 1.f / T;
    e0.x *= inv; e0.y *= inv; e0.z *= inv; e0.w *= inv;
    e1.x *= inv; e1.y *= inv; e1.z *= inv; e1.w *= inv;
    row4[t] = e0;
    row4[t + 1024] = e1;
}

// ---------------- K4: wc[b,d] += sum_s attn[b,s]*ctx[b,s,d] (chunked, atomics into ws)
#define CH 512
__global__ __launch_bounds__(256) void wsum_kernel(const float* __restrict__ ctx,
                                                   const float* __restrict__ attn,
                                                   float* __restrict__ wc) {
    const int t = threadIdx.x;
    const int b = blockIdx.x >> 4;      // 16 chunks per batch
    const int chunk = blockIdx.x & 15;
    const int c2 = t & 63;              // float2 column (covers 128 floats)
    const int rg = t >> 6;              // row group 0..3
    const float2* ctx2 = (const float2*)(ctx + ((size_t)b * SS + (size_t)chunk * CH) * DD);
    const float* arow = attn + (size_t)b * SS + (size_t)chunk * CH;
    float2 acc = {0.f, 0.f};
#pragma unroll 4
    for (int s = rg; s < CH; s += 4) {
        float a = arow[s];
        float2 v = ctx2[(size_t)s * 64 + c2];
        acc.x += a * v.x;
        acc.y += a * v.y;
    }
    __shared__ float2 part[256];
    part[t] = acc;
    __syncthreads();
    if (t < 64) {
        float2 r = part[t];
        float2 p1 = part[t + 64], p2 = part[t + 128], p3 = part[t + 192];
        r.x += p1.x + p2.x + p3.x;
        r.y += p1.y + p2.y + p3.y;
        atomicAdd(&wc[b * DD + 2 * c2], r.x);
        atomicAdd(&wc[b * DD + 2 * c2 + 1], r.y);
    }
}

// ---------------- K5: h = tanh(concat(wc, q) @ W_out^T)
__global__ void out_kernel(const float* __restrict__ wc,
                           const float* __restrict__ q,
                           const float* __restrict__ W_out,
                           float* __restrict__ h) {
    __shared__ float cat[2 * DD];
    const int b = blockIdx.x, d = threadIdx.x;  // 128 threads
    cat[d] = wc[b * DD + d];
    cat[DD + d] = q[b * DD + d];
    __syncthreads();
    const float4* wrow = (const float4*)(W_out + (size_t)d * 2 * DD);
    float acc = 0.f;
#pragma unroll
    for (int k4 = 0; k4 < 2 * DD / 4; k4++) {
        float4 w = wrow[k4];
        float4 x = ((const float4*)cat)[k4];
        acc += w.x * x.x + w.y * x.y + w.z * x.z + w.w * x.w;
    }
    h[b * DD + d] = tanh_fast(acc);
}

extern "C" void kernel_launch(void* const* d_in, const int* in_sizes, int n_in,
                              void* d_out, int out_size, void* d_ws, size_t ws_size,
                              hipStream_t stream) {
    const float* input = (const float*)d_in[0];
    const float* ctx   = (const float*)d_in[1];
    const float* W_enc = (const float*)d_in[2];
    const float* b_enc = (const float*)d_in[3];
    const float* W_dec = (const float*)d_in[4];
    const float* b_dec = (const float*)d_in[5];
    const float* W_out = (const float*)d_in[6];

    float* h    = (float*)d_out;            // [B, D]
    float* attn = (float*)d_out + BB * DD;  // [B, S] (scores in-place -> softmax)
    float* q    = (float*)d_ws;             // [B, D]
    float* wc   = (float*)d_ws + BB * DD;   // [B, D] accumulators (zeroed in K1)

    qproj_kernel<<<BB, DD, 0, stream>>>(input, W_dec, b_dec, q, wc);
    score_kernel<<<1024, 256, 0, stream>>>(ctx, W_enc, b_enc, q, attn);
    softmax_kernel<<<BB, 1024, 0, stream>>>(attn);
    wsum_kernel<<<BB * 16, 256, 0, stream>>>(ctx, attn, wc);
    out_kernel<<<BB, DD, 0, stream>>>(wc, q, W_out, h);
}